// Round 1
// baseline (397.883 us; speedup 1.0000x reference)
//
#include <hip/hip_runtime.h>

// LightLIF fused step on MI355X (gfx950).
//
//   A = [inputs | z]            : [4096, 3072] fp32   (M x K)
//   Bm = [w_in ; w_rec*(1-eye)] : [3072, 2048] fp32   (K x N), B pre-scaled by 256
//   i_t = A @ Bm                                     (fp32-accurate via f16 split MFMA)
//   new_v = DECAY*v + (1-DECAY)*i_t - 0.615*z
//   new_z = ((new_v - 0.615)/0.615 > 0.615) ? 1 : 0
//   d_out = [new_z (M*N) | new_v (M*N)]
//
// Precision scheme (Markidis split, 22-bit mantissa ~= fp32):
//   x = hi + lo * 2^-11,  hi = f16(x), lo = f16((x - hi)*2048)   [lo scaled by 2^11
//   so it stays in f16 normal range; B additionally scaled by 256 so hi parts of
//   small weights are normal — avoids any dependence on MFMA denormal handling]
//   acc0 += hi_a*hi_b ; acc1 += hi_a*lo_b + lo_a*hi_b
//   i_t  = acc0/256 + acc1/(2048*256)          (exact power-of-2 rescales)
//   dropped lo*lo term ~ 2^-22 relative — below fp32 reorder noise.

#define M_DIM 4096
#define N_DIM 2048
#define K_DIM 3072
#define KA    1024          // width of `inputs` (rest of K comes from z / w_rec)
#define BK    32
#define LDK   40            // padded LDS k-stride in halves (80B rows: conflict-free)
#define NSTEP (K_DIM / BK)  // 96

typedef _Float16 f16x8 __attribute__((ext_vector_type(8)));
typedef float    f32x4 __attribute__((ext_vector_type(4)));

// hi/lo split with lo pre-scaled by 2048 (RNE conversions)
#define SPLIT(x, dsthi, dstlo, idx)                                  \
  {                                                                  \
    _Float16 _h = (_Float16)(x);                                     \
    float    _r = ((x) - (float)_h) * 2048.0f;                       \
    dsthi[idx] = _h;                                                 \
    dstlo[idx] = (_Float16)_r;                                       \
  }

__global__ __launch_bounds__(256, 2) void lif_kernel(
    const float* __restrict__ inputs, const float* __restrict__ vin,
    const float* __restrict__ zin, const float* __restrict__ w_in,
    const float* __restrict__ w_rec, float* __restrict__ out) {
  // ---- LDS tiles: A[128][BK], Bt[128 n][BK k], hi+lo each, padded to LDK ----
  __shared__ __align__(16) _Float16 sAhi[128 * LDK];
  __shared__ __align__(16) _Float16 sAlo[128 * LDK];
  __shared__ __align__(16) _Float16 sBhi[128 * LDK];
  __shared__ __align__(16) _Float16 sBlo[128 * LDK];

  const int tid = threadIdx.x;
  const int bn = blockIdx.x;   // n-tile (16)
  const int bm = blockIdx.y;   // m-tile (32)

  // staging assignment: each thread owns one LDS row (A-row or B-col) and a k-half
  const int srow = tid & 127;  // A row within tile / B col within tile
  const int skh  = tid >> 7;   // 0/1 -> k in [skh*16, skh*16+16)

  // compute assignment: 4 waves in 2x2 of 64x64
  const int lane = tid & 63;
  const int wid  = tid >> 6;
  const int wm   = wid & 1;
  const int wn   = wid >> 1;
  const int lr   = lane & 15;  // row of A-frag / col of B-frag / col of C
  const int kg   = lane >> 4;  // k-group (8 halves each)

  const int aoff = (wm * 64 + lr) * LDK + kg * 8;
  const int boff = (wn * 64 + lr) * LDK + kg * 8;

  f32x4 acc0[4][4];  // hi*hi
  f32x4 acc1[4][4];  // hi*lo + lo*hi  (scale 2^11 * 256)
#pragma unroll
  for (int i = 0; i < 4; ++i)
#pragma unroll
    for (int j = 0; j < 4; ++j) {
      acc0[i][j] = (f32x4)0.0f;
      acc1[i][j] = (f32x4)0.0f;
    }

  const int rowg = bm * 128 + srow;  // global A row this thread stages
  const int ng   = bn * 128 + srow;  // global B col this thread stages

  for (int kt = 0; kt < NSTEP; ++kt) {
    const int k0 = kt * BK;

    // ---------- load + split A micro-row (16 f32, one 64B line) ----------
    f16x8 ahi[2], alo[2];
    {
      const float* aptr = (k0 < KA)
          ? inputs + (size_t)rowg * KA + (k0 + skh * 16)
          : zin + (size_t)rowg * N_DIM + (k0 - KA + skh * 16);
#pragma unroll
      for (int q = 0; q < 4; ++q) {
        const float4 f = *(const float4*)(aptr + q * 4);
        const int vi = q >> 1, ei = (q & 1) * 4;
        SPLIT(f.x, ahi[vi], alo[vi], ei + 0);
        SPLIT(f.y, ahi[vi], alo[vi], ei + 1);
        SPLIT(f.z, ahi[vi], alo[vi], ei + 2);
        SPLIT(f.w, ahi[vi], alo[vi], ei + 3);
      }
    }

    // ---------- load + split B micro-col (16 f32 down k), transpose in regs ----------
    f16x8 bhi[2], blo[2];
    {
      const bool isrec = (k0 >= KA);
      const int kbase = k0 - KA + skh * 16;  // row index inside w_rec (if isrec)
      const float* bptr = isrec
          ? w_rec + (size_t)kbase * N_DIM + ng
          : w_in + (size_t)(k0 + skh * 16) * N_DIM + ng;
#pragma unroll
      for (int kk = 0; kk < 16; ++kk) {
        float x = bptr[(size_t)kk * N_DIM];
        if (isrec && (kbase + kk == ng)) x = 0.0f;  // zero diagonal of w_rec
        x *= 256.0f;                                // keep hi-parts of w normal in f16
        SPLIT(x, bhi[kk >> 3], blo[kk >> 3], kk & 7);
      }
    }

    __syncthreads();  // previous iteration's frag reads complete

    // ---------- write staged halves to LDS (b128, conflict-free groups) ----------
    {
      _Float16* pA = &sAhi[srow * LDK + skh * 16];
      *(f16x8*)(pA + 0) = ahi[0];
      *(f16x8*)(pA + 8) = ahi[1];
      _Float16* pAl = &sAlo[srow * LDK + skh * 16];
      *(f16x8*)(pAl + 0) = alo[0];
      *(f16x8*)(pAl + 8) = alo[1];
      _Float16* pB = &sBhi[srow * LDK + skh * 16];
      *(f16x8*)(pB + 0) = bhi[0];
      *(f16x8*)(pB + 8) = bhi[1];
      _Float16* pBl = &sBlo[srow * LDK + skh * 16];
      *(f16x8*)(pBl + 0) = blo[0];
      *(f16x8*)(pBl + 8) = blo[1];
    }

    __syncthreads();

    // ---------- fragments + 48 MFMA ----------
    f16x8 ah[4], al[4];
#pragma unroll
    for (int i = 0; i < 4; ++i) {
      ah[i] = *(const f16x8*)&sAhi[aoff + i * 16 * LDK];
      al[i] = *(const f16x8*)&sAlo[aoff + i * 16 * LDK];
    }
#pragma unroll
    for (int j = 0; j < 4; ++j) {
      const f16x8 bh = *(const f16x8*)&sBhi[boff + j * 16 * LDK];
      const f16x8 bl = *(const f16x8*)&sBlo[boff + j * 16 * LDK];
      // three passes so same-acc MFMAs are >=4 apart (hide MFMA latency)
#pragma unroll
      for (int i = 0; i < 4; ++i)
        acc0[i][j] = __builtin_amdgcn_mfma_f32_16x16x32_f16(ah[i], bh, acc0[i][j], 0, 0, 0);
#pragma unroll
      for (int i = 0; i < 4; ++i)
        acc1[i][j] = __builtin_amdgcn_mfma_f32_16x16x32_f16(ah[i], bl, acc1[i][j], 0, 0, 0);
#pragma unroll
      for (int i = 0; i < 4; ++i)
        acc1[i][j] = __builtin_amdgcn_mfma_f32_16x16x32_f16(al[i], bh, acc1[i][j], 0, 0, 0);
    }
  }

  // ---------- fused LIF epilogue ----------
  // DECAY exactly mirrors np.float32(np.exp(-1/20))
  const float DECAYF = 0.9512294245007140f;
  const float OMD    = 1.0f - DECAYF;
  const float THR    = 0.615f;

  float* outZ = out;
  float* outV = out + (size_t)M_DIM * N_DIM;
  const int colbase = bn * 128 + wn * 64;
  const int rowbase = bm * 128 + wm * 64 + kg * 4;

#pragma unroll
  for (int i = 0; i < 4; ++i) {
#pragma unroll
    for (int j = 0; j < 4; ++j) {
      const int col = colbase + j * 16 + lr;
#pragma unroll
      for (int r = 0; r < 4; ++r) {
        const int row = rowbase + i * 16 + r;
        const size_t idx = (size_t)row * N_DIM + col;
        // undo scales: acc0 carries 256x, acc1 carries 256*2048x
        const float it = acc0[i][j][r] * (1.0f / 256.0f) +
                         acc1[i][j][r] * (1.0f / 524288.0f);
        const float vv = vin[idx];
        const float zz = zin[idx];
        const float nv = DECAYF * vv + OMD * it - THR * zz;   // I_reset = z*THR*DT
        const float vs = (nv - THR) / THR;
        outZ[idx] = (vs > THR) ? 1.0f : 0.0f;  // spike * (1/DT)
        outV[idx] = nv;
      }
    }
  }
}

extern "C" void kernel_launch(void* const* d_in, const int* in_sizes, int n_in,
                              void* d_out, int out_size, void* d_ws, size_t ws_size,
                              hipStream_t stream) {
  const float* inputs = (const float*)d_in[0];
  const float* v      = (const float*)d_in[1];
  const float* z      = (const float*)d_in[2];
  const float* w_in   = (const float*)d_in[3];
  const float* w_rec  = (const float*)d_in[4];
  float* out = (float*)d_out;

  dim3 grid(N_DIM / 128, M_DIM / 128);  // (16, 32) = 512 blocks
  dim3 block(256);
  hipLaunchKernelGGL(lif_kernel, grid, block, 0, stream,
                     inputs, v, z, w_in, w_rec, out);
}

// Round 2
// 334.276 us; speedup vs baseline: 1.1903x; 1.1903x over previous
//
#include <hip/hip_runtime.h>

// LightLIF fused step on MI355X (gfx950) — round 2.
//
//   A = [inputs | z]            : [4096, 3072] fp32   (M x K)
//   Bm = [w_in ; w_rec*(1-eye)] : [3072, 2048] fp32   (K x N), B pre-scaled by 256
//   i_t = A @ Bm    (fp32-accurate via f16 Markidis split, 3 MFMA passes)
//   new_v = DECAY*v + (1-DECAY)*i_t - 0.615*z ; spike vs THR
//   d_out = [new_z (M*N) | new_v (M*N)]
//
// Round-2 structure: prep kernels split A and B ONCE into f16 hi/lo stored in
// LDS-image layout (tiles of 128 rows x 40 halves, pad included) in d_ws.
// GEMM K-loop stages images with global_load_lds width=16 (no VGPR round-trip,
// no per-K split VALU work), then ds_read_b128 frags + 48 MFMA per wave.
// Falls back to the round-1 monolithic kernel if ws_size < 94.4 MB.

#define M_DIM 4096
#define N_DIM 2048
#define K_DIM 3072
#define KA    1024
#define BK    32
#define LDK   40                    // padded k-stride in halves (80 B rows)
#define NSTEP (K_DIM / BK)          // 96
#define IMG_HALVES (128 * LDK)      // 5120 halves
#define IMG_BYTES  (IMG_HALVES * 2) // 10240 B

#define SZ_A ((size_t)32 * 96 * IMG_BYTES)  // 31,457,280 B (one of hi/lo)
#define SZ_B ((size_t)16 * 96 * IMG_BYTES)  // 15,728,640 B
#define WS_NEEDED (2 * SZ_A + 2 * SZ_B)     // 94,371,840 B

typedef _Float16 f16x8 __attribute__((ext_vector_type(8)));
typedef _Float16 f16x4 __attribute__((ext_vector_type(4)));
typedef float    f32x4 __attribute__((ext_vector_type(4)));

#define GLOBAL_AS(p) ((const __attribute__((address_space(1))) void*)(p))
#define LDS_AS(p)    ((__attribute__((address_space(3))) void*)(p))

// hi/lo split with lo pre-scaled by 2048 (RNE conversions)
#define SPLIT(x, dsthi, dstlo, idx)                                  \
  {                                                                  \
    _Float16 _h = (_Float16)(x);                                     \
    float    _r = ((x) - (float)_h) * 2048.0f;                       \
    dsthi[idx] = _h;                                                 \
    dstlo[idx] = (_Float16)_r;                                       \
  }

// ---------------------------------------------------------------------------
// prep_a: split [inputs|z] rows into (hi,lo) f16 tile-images.
// grid (96 kt, 32 bm), block 256. Image = 128 rows x 40 halves (32 real).
// Lane groups of 8 read 128 B contiguous per row — coalesced-enough.
// ---------------------------------------------------------------------------
__global__ void prep_a(const float* __restrict__ inputs,
                       const float* __restrict__ z,
                       _Float16* __restrict__ ahi, _Float16* __restrict__ alo) {
  const int kt = blockIdx.x, bm = blockIdx.y;
  const int t = threadIdx.x;
  const int s = t & 7;       // 16B chunk within the row's 128 B
  const int rb = t >> 3;     // 0..31
  const int k0 = kt * BK;
  const size_t img = ((size_t)bm * 96 + kt) * IMG_HALVES;
#pragma unroll
  for (int p = 0; p < 4; ++p) {
    const int r = p * 32 + rb;
    const int rg = bm * 128 + r;
    const int ks = k0 + s * 4;
    const float* src = (k0 < KA) ? inputs + (size_t)rg * KA + ks
                                 : z + (size_t)rg * N_DIM + (ks - KA);
    const float4 f = *(const float4*)src;
    f16x4 hi, lo;
    SPLIT(f.x, hi, lo, 0);
    SPLIT(f.y, hi, lo, 1);
    SPLIT(f.z, hi, lo, 2);
    SPLIT(f.w, hi, lo, 3);
    *(f16x4*)&ahi[img + (size_t)r * LDK + s * 4] = hi;
    *(f16x4*)&alo[img + (size_t)r * LDK + s * 4] = lo;
  }
}

// ---------------------------------------------------------------------------
// prep_b: split w (scaled x256, diag-masked) into (hi,lo) f16 tile-images,
// transposed: image row = output column. grid (96 kt, 16 bn), block 128.
// Each thread owns one column; reads are fully coalesced across lanes per kk.
// ---------------------------------------------------------------------------
__global__ void prep_b(const float* __restrict__ w_in,
                       const float* __restrict__ w_rec,
                       _Float16* __restrict__ bhi, _Float16* __restrict__ blo) {
  const int kt = blockIdx.x, bn = blockIdx.y;
  const int c = threadIdx.x;      // 0..127
  const int ng = bn * 128 + c;
  const int k0 = kt * BK;
  _Float16 hi[BK], lo[BK];
#pragma unroll
  for (int kk = 0; kk < BK; ++kk) {
    const int k = k0 + kk;
    float x = (k < KA) ? w_in[(size_t)k * N_DIM + ng]
                       : w_rec[(size_t)(k - KA) * N_DIM + ng];
    if (k >= KA && (k - KA) == ng) x = 0.0f;   // zero diagonal of w_rec
    x *= 256.0f;                               // keep hi-parts normal in f16
    SPLIT(x, hi, lo, kk);
  }
  const size_t img = ((size_t)bn * 96 + kt) * IMG_HALVES + (size_t)c * LDK;
#pragma unroll
  for (int q = 0; q < 4; ++q) {
    *(f16x8*)&bhi[img + q * 8] = *(const f16x8*)&hi[q * 8];
    *(f16x8*)&blo[img + q * 8] = *(const f16x8*)&lo[q * 8];
  }
}

// ---------------------------------------------------------------------------
// GEMM + fused LIF epilogue. grid (16 bn, 32 bm), block 256 (4 waves, 2x2 of
// 64x64). Wave w DMA-stages image w (Ahi/Alo/Bhi/Blo) via global_load_lds.
// ---------------------------------------------------------------------------
__global__ __launch_bounds__(256, 2) void lif_gemm(
    const _Float16* __restrict__ ahi, const _Float16* __restrict__ alo,
    const _Float16* __restrict__ bhi, const _Float16* __restrict__ blo,
    const float* __restrict__ vin, const float* __restrict__ zin,
    float* __restrict__ out) {
  __shared__ __align__(16) _Float16 sAhi[IMG_HALVES];
  __shared__ __align__(16) _Float16 sAlo[IMG_HALVES];
  __shared__ __align__(16) _Float16 sBhi[IMG_HALVES];
  __shared__ __align__(16) _Float16 sBlo[IMG_HALVES];

  const int tid = threadIdx.x;
  const int bn = blockIdx.x;
  const int bm = blockIdx.y;
  const int lane = tid & 63;
  const int wid = tid >> 6;
  const int wm = wid & 1;
  const int wn = wid >> 1;
  const int lr = lane & 15;
  const int kg = lane >> 4;

  // staging role: wave -> one image stream
  const _Float16* gsrc;
  _Float16* ldst;
  if (wid == 0)      { gsrc = ahi + (size_t)bm * 96 * IMG_HALVES; ldst = sAhi; }
  else if (wid == 1) { gsrc = alo + (size_t)bm * 96 * IMG_HALVES; ldst = sAlo; }
  else if (wid == 2) { gsrc = bhi + (size_t)bn * 96 * IMG_HALVES; ldst = sBhi; }
  else               { gsrc = blo + (size_t)bn * 96 * IMG_HALVES; ldst = sBlo; }
  gsrc += (size_t)lane * 8;  // per-lane 16 B

  const int aoff = (wm * 64 + lr) * LDK + kg * 8;
  const int boff = (wn * 64 + lr) * LDK + kg * 8;

  f32x4 acc0[4][4];  // hi*hi (scale 256)
  f32x4 acc1[4][4];  // hi*lo + lo*hi (scale 256*2048)
#pragma unroll
  for (int i = 0; i < 4; ++i)
#pragma unroll
    for (int j = 0; j < 4; ++j) {
      acc0[i][j] = (f32x4)0.0f;
      acc1[i][j] = (f32x4)0.0f;
    }

  for (int kt = 0; kt < NSTEP; ++kt) {
    __syncthreads();  // previous iteration's frag reads complete
    const _Float16* g = gsrc + (size_t)kt * IMG_HALVES;
#pragma unroll
    for (int q = 0; q < 10; ++q)
      __builtin_amdgcn_global_load_lds(GLOBAL_AS(g + q * 512),
                                       LDS_AS(ldst + q * 512), 16, 0, 0);
    __syncthreads();  // images staged (vmcnt(0) drain)

    f16x8 ah[4], al[4];
#pragma unroll
    for (int i = 0; i < 4; ++i) {
      ah[i] = *(const f16x8*)&sAhi[aoff + i * 16 * LDK];
      al[i] = *(const f16x8*)&sAlo[aoff + i * 16 * LDK];
    }
#pragma unroll
    for (int j = 0; j < 4; ++j) {
      const f16x8 bh = *(const f16x8*)&sBhi[boff + j * 16 * LDK];
      const f16x8 bl = *(const f16x8*)&sBlo[boff + j * 16 * LDK];
#pragma unroll
      for (int i = 0; i < 4; ++i)
        acc0[i][j] = __builtin_amdgcn_mfma_f32_16x16x32_f16(ah[i], bh, acc0[i][j], 0, 0, 0);
#pragma unroll
      for (int i = 0; i < 4; ++i)
        acc1[i][j] = __builtin_amdgcn_mfma_f32_16x16x32_f16(ah[i], bl, acc1[i][j], 0, 0, 0);
#pragma unroll
      for (int i = 0; i < 4; ++i)
        acc1[i][j] = __builtin_amdgcn_mfma_f32_16x16x32_f16(al[i], bh, acc1[i][j], 0, 0, 0);
    }
  }

  // fused LIF epilogue
  const float DECAYF = 0.9512294245007140f;
  const float OMD = 1.0f - DECAYF;
  const float THR = 0.615f;

  float* outZ = out;
  float* outV = out + (size_t)M_DIM * N_DIM;
  const int colbase = bn * 128 + wn * 64;
  const int rowbase = bm * 128 + wm * 64 + kg * 4;

#pragma unroll
  for (int i = 0; i < 4; ++i) {
#pragma unroll
    for (int j = 0; j < 4; ++j) {
      const int col = colbase + j * 16 + lr;
#pragma unroll
      for (int r = 0; r < 4; ++r) {
        const int row = rowbase + i * 16 + r;
        const size_t idx = (size_t)row * N_DIM + col;
        const float it = acc0[i][j][r] * (1.0f / 256.0f) +
                         acc1[i][j][r] * (1.0f / 524288.0f);
        const float vv = vin[idx];
        const float zz = zin[idx];
        const float nv = DECAYF * vv + OMD * it - THR * zz;
        const float vs = (nv - THR) / THR;
        outZ[idx] = (vs > THR) ? 1.0f : 0.0f;
        outV[idx] = nv;
      }
    }
  }
}

// ---------------------------------------------------------------------------
// Fallback (round-1 monolithic kernel) — used only if ws_size < WS_NEEDED.
// ---------------------------------------------------------------------------
__global__ __launch_bounds__(256, 2) void lif_kernel(
    const float* __restrict__ inputs, const float* __restrict__ vin,
    const float* __restrict__ zin, const float* __restrict__ w_in,
    const float* __restrict__ w_rec, float* __restrict__ out) {
  __shared__ __align__(16) _Float16 sAhi[128 * LDK];
  __shared__ __align__(16) _Float16 sAlo[128 * LDK];
  __shared__ __align__(16) _Float16 sBhi[128 * LDK];
  __shared__ __align__(16) _Float16 sBlo[128 * LDK];

  const int tid = threadIdx.x;
  const int bn = blockIdx.x;
  const int bm = blockIdx.y;
  const int srow = tid & 127;
  const int skh = tid >> 7;
  const int lane = tid & 63;
  const int wid = tid >> 6;
  const int wm = wid & 1;
  const int wn = wid >> 1;
  const int lr = lane & 15;
  const int kg = lane >> 4;
  const int aoff = (wm * 64 + lr) * LDK + kg * 8;
  const int boff = (wn * 64 + lr) * LDK + kg * 8;

  f32x4 acc0[4][4];
  f32x4 acc1[4][4];
#pragma unroll
  for (int i = 0; i < 4; ++i)
#pragma unroll
    for (int j = 0; j < 4; ++j) {
      acc0[i][j] = (f32x4)0.0f;
      acc1[i][j] = (f32x4)0.0f;
    }

  const int rowg = bm * 128 + srow;
  const int ng = bn * 128 + srow;

  for (int kt = 0; kt < NSTEP; ++kt) {
    const int k0 = kt * BK;
    f16x8 ahi[2], alo[2];
    {
      const float* aptr = (k0 < KA)
          ? inputs + (size_t)rowg * KA + (k0 + skh * 16)
          : zin + (size_t)rowg * N_DIM + (k0 - KA + skh * 16);
#pragma unroll
      for (int q = 0; q < 4; ++q) {
        const float4 f = *(const float4*)(aptr + q * 4);
        const int vi = q >> 1, ei = (q & 1) * 4;
        SPLIT(f.x, ahi[vi], alo[vi], ei + 0);
        SPLIT(f.y, ahi[vi], alo[vi], ei + 1);
        SPLIT(f.z, ahi[vi], alo[vi], ei + 2);
        SPLIT(f.w, ahi[vi], alo[vi], ei + 3);
      }
    }
    f16x8 bhi[2], blo[2];
    {
      const bool isrec = (k0 >= KA);
      const int kbase = k0 - KA + skh * 16;
      const float* bptr = isrec
          ? w_rec + (size_t)kbase * N_DIM + ng
          : w_in + (size_t)(k0 + skh * 16) * N_DIM + ng;
#pragma unroll
      for (int kk = 0; kk < 16; ++kk) {
        float x = bptr[(size_t)kk * N_DIM];
        if (isrec && (kbase + kk == ng)) x = 0.0f;
        x *= 256.0f;
        SPLIT(x, bhi[kk >> 3], blo[kk >> 3], kk & 7);
      }
    }

    __syncthreads();
    {
      _Float16* pA = &sAhi[srow * LDK + skh * 16];
      *(f16x8*)(pA + 0) = ahi[0];
      *(f16x8*)(pA + 8) = ahi[1];
      _Float16* pAl = &sAlo[srow * LDK + skh * 16];
      *(f16x8*)(pAl + 0) = alo[0];
      *(f16x8*)(pAl + 8) = alo[1];
      _Float16* pB = &sBhi[srow * LDK + skh * 16];
      *(f16x8*)(pB + 0) = bhi[0];
      *(f16x8*)(pB + 8) = bhi[1];
      _Float16* pBl = &sBlo[srow * LDK + skh * 16];
      *(f16x8*)(pBl + 0) = blo[0];
      *(f16x8*)(pBl + 8) = blo[1];
    }
    __syncthreads();

    f16x8 ah[4], al[4];
#pragma unroll
    for (int i = 0; i < 4; ++i) {
      ah[i] = *(const f16x8*)&sAhi[aoff + i * 16 * LDK];
      al[i] = *(const f16x8*)&sAlo[aoff + i * 16 * LDK];
    }
#pragma unroll
    for (int j = 0; j < 4; ++j) {
      const f16x8 bh = *(const f16x8*)&sBhi[boff + j * 16 * LDK];
      const f16x8 bl = *(const f16x8*)&sBlo[boff + j * 16 * LDK];
#pragma unroll
      for (int i = 0; i < 4; ++i)
        acc0[i][j] = __builtin_amdgcn_mfma_f32_16x16x32_f16(ah[i], bh, acc0[i][j], 0, 0, 0);
#pragma unroll
      for (int i = 0; i < 4; ++i)
        acc1[i][j] = __builtin_amdgcn_mfma_f32_16x16x32_f16(ah[i], bl, acc1[i][j], 0, 0, 0);
#pragma unroll
      for (int i = 0; i < 4; ++i)
        acc1[i][j] = __builtin_amdgcn_mfma_f32_16x16x32_f16(al[i], bh, acc1[i][j], 0, 0, 0);
    }
  }

  const float DECAYF = 0.9512294245007140f;
  const float OMD = 1.0f - DECAYF;
  const float THR = 0.615f;
  float* outZ = out;
  float* outV = out + (size_t)M_DIM * N_DIM;
  const int colbase = bn * 128 + wn * 64;
  const int rowbase = bm * 128 + wm * 64 + kg * 4;
#pragma unroll
  for (int i = 0; i < 4; ++i) {
#pragma unroll
    for (int j = 0; j < 4; ++j) {
      const int col = colbase + j * 16 + lr;
#pragma unroll
      for (int r = 0; r < 4; ++r) {
        const int row = rowbase + i * 16 + r;
        const size_t idx = (size_t)row * N_DIM + col;
        const float it = acc0[i][j][r] * (1.0f / 256.0f) +
                         acc1[i][j][r] * (1.0f / 524288.0f);
        const float vv = vin[idx];
        const float zz = zin[idx];
        const float nv = DECAYF * vv + OMD * it - THR * zz;
        const float vs = (nv - THR) / THR;
        outZ[idx] = (vs > THR) ? 1.0f : 0.0f;
        outV[idx] = nv;
      }
    }
  }
}

extern "C" void kernel_launch(void* const* d_in, const int* in_sizes, int n_in,
                              void* d_out, int out_size, void* d_ws, size_t ws_size,
                              hipStream_t stream) {
  const float* inputs = (const float*)d_in[0];
  const float* v      = (const float*)d_in[1];
  const float* z      = (const float*)d_in[2];
  const float* w_in   = (const float*)d_in[3];
  const float* w_rec  = (const float*)d_in[4];
  float* out = (float*)d_out;

  if (ws_size >= WS_NEEDED) {
    _Float16* ahi = (_Float16*)d_ws;
    _Float16* alo = (_Float16*)((char*)d_ws + SZ_A);
    _Float16* bhi = (_Float16*)((char*)d_ws + 2 * SZ_A);
    _Float16* blo = (_Float16*)((char*)d_ws + 2 * SZ_A + SZ_B);
    hipLaunchKernelGGL(prep_a, dim3(96, 32), dim3(256), 0, stream,
                       inputs, z, ahi, alo);
    hipLaunchKernelGGL(prep_b, dim3(96, 16), dim3(128), 0, stream,
                       w_in, w_rec, bhi, blo);
    hipLaunchKernelGGL(lif_gemm, dim3(16, 32), dim3(256), 0, stream,
                       ahi, alo, bhi, blo, v, z, out);
  } else {
    hipLaunchKernelGGL(lif_kernel, dim3(16, 32), dim3(256), 0, stream,
                       inputs, v, z, w_in, w_rec, out);
  }
}

// Round 3
// 310.811 us; speedup vs baseline: 1.2801x; 1.0755x over previous
//
#include <hip/hip_runtime.h>

// LightLIF fused step on MI355X (gfx950) — round 3.
//
//   A = [inputs | z]            : [4096, 3072] fp32   (M x K)
//   Bm = [w_in ; w_rec*(1-eye)] : [3072, 2048] fp32   (K x N), B pre-scaled by 256
//   i_t = A @ Bm    (fp32-accurate via f16 Markidis split, 3 MFMA passes)
//   new_v = DECAY*v + (1-DECAY)*i_t - 0.615*z ; spike vs THR
//   d_out = [new_z (M*N) | new_v (M*N)]
//
// Round-3: images stored UNPADDED in k-octet-major layout img[kg][row][8]
// (8 KB per 128x32 tile) -> dense coalesced prep stores, conflict-free
// ds_read_b128 frag reads (each 16-lane phase reads 256 B contiguous), and
// double-buffered LDS (64 KB) with one barrier per K-step: the DMA prefetch
// for kt+1 is drained a full iteration later, making the vmcnt(0) drain free.

#define M_DIM 4096
#define N_DIM 2048
#define K_DIM 3072
#define KA    1024
#define BK    32
#define NSTEP (K_DIM / BK)          // 96
#define IMG_HALVES 4096             // 4 k-octets x 128 rows x 8 halves
#define IMG_BYTES  8192

#define SZ_A ((size_t)32 * 96 * IMG_BYTES)  // 25,165,824 B (one of hi/lo)
#define SZ_B ((size_t)16 * 96 * IMG_BYTES)  // 12,582,912 B
#define WS_NEEDED (2 * SZ_A + 2 * SZ_B)     // 75,497,472 B

typedef _Float16 f16x8 __attribute__((ext_vector_type(8)));
typedef _Float16 f16x4 __attribute__((ext_vector_type(4)));
typedef float    f32x4 __attribute__((ext_vector_type(4)));

#define GLOBAL_AS(p) ((const __attribute__((address_space(1))) void*)(p))
#define LDS_AS(p)    ((__attribute__((address_space(3))) void*)(p))

// hi/lo split with lo pre-scaled by 2048 (RNE conversions)
#define SPLIT(x, dsthi, dstlo, idx)                                  \
  {                                                                  \
    _Float16 _h = (_Float16)(x);                                     \
    float    _r = ((x) - (float)_h) * 2048.0f;                       \
    dsthi[idx] = _h;                                                 \
    dstlo[idx] = (_Float16)_r;                                       \
  }

// ---------------------------------------------------------------------------
// prep_a: split [inputs|z] into (hi,lo) f16 images, layout img[kg][row][8].
// grid (96 kt, 32 bm), block 256. Thread: row r = t&127, k-half kh = t>>7.
// Reads 64 B contiguous per thread; stores are 16 B/lane dense-coalesced.
// ---------------------------------------------------------------------------
__global__ void prep_a(const float* __restrict__ inputs,
                       const float* __restrict__ z,
                       _Float16* __restrict__ ahi, _Float16* __restrict__ alo) {
  const int kt = blockIdx.x, bm = blockIdx.y;
  const int t = threadIdx.x;
  const int r = t & 127;
  const int kh = t >> 7;               // 0/1 -> which 16-float half of BK
  const int rg = bm * 128 + r;
  const int k0 = kt * BK + kh * 16;
  const float* src = (kt < 32) ? inputs + (size_t)rg * KA + k0
                               : z + (size_t)rg * N_DIM + (k0 - KA);
  f16x8 hi[2], lo[2];
#pragma unroll
  for (int q = 0; q < 4; ++q) {
    const float4 f = *(const float4*)(src + q * 4);
    const int vi = q >> 1, ei = (q & 1) * 4;
    SPLIT(f.x, hi[vi], lo[vi], ei + 0);
    SPLIT(f.y, hi[vi], lo[vi], ei + 1);
    SPLIT(f.z, hi[vi], lo[vi], ei + 2);
    SPLIT(f.w, hi[vi], lo[vi], ei + 3);
  }
  const size_t img = ((size_t)bm * 96 + kt) * IMG_HALVES;
  const size_t o0 = img + (size_t)(2 * kh) * 1024 + (size_t)r * 8;
  *(f16x8*)&ahi[o0]        = hi[0];
  *(f16x8*)&ahi[o0 + 1024] = hi[1];
  *(f16x8*)&alo[o0]        = lo[0];
  *(f16x8*)&alo[o0 + 1024] = lo[1];
}

// ---------------------------------------------------------------------------
// prep_b: split w (x256, diag-masked) into transposed images img[kg][col][8].
// grid (96 kt, 16 bn), block 128; thread owns one output column.
// Reads coalesced across lanes at each k; stores 16 B/lane dense-coalesced.
// ---------------------------------------------------------------------------
__global__ void prep_b(const float* __restrict__ w_in,
                       const float* __restrict__ w_rec,
                       _Float16* __restrict__ bhi, _Float16* __restrict__ blo) {
  const int kt = blockIdx.x, bn = blockIdx.y;
  const int c = threadIdx.x;      // 0..127
  const int ng = bn * 128 + c;
  const int k0 = kt * BK;
  f16x8 hi[4], lo[4];
#pragma unroll
  for (int kk = 0; kk < BK; ++kk) {
    const int k = k0 + kk;
    float x = (k < KA) ? w_in[(size_t)k * N_DIM + ng]
                       : w_rec[(size_t)(k - KA) * N_DIM + ng];
    if (k >= KA && (k - KA) == ng) x = 0.0f;   // zero diagonal of w_rec
    x *= 256.0f;                               // keep hi-parts normal in f16
    SPLIT(x, hi[kk >> 3], lo[kk >> 3], kk & 7);
  }
  const size_t img = ((size_t)bn * 96 + kt) * IMG_HALVES + (size_t)c * 8;
#pragma unroll
  for (int q = 0; q < 4; ++q) {
    *(f16x8*)&bhi[img + (size_t)q * 1024] = hi[q];
    *(f16x8*)&blo[img + (size_t)q * 1024] = lo[q];
  }
}

// ---------------------------------------------------------------------------
// GEMM + fused LIF epilogue. grid (16 bn, 32 bm), block 256 (4 waves, 2x2 of
// 64x64). Double-buffered LDS; wave wid DMA-stages image wid for kt+1 each
// iteration; ONE barrier per K-step.
// ---------------------------------------------------------------------------
__global__ __launch_bounds__(256, 2) void lif_gemm(
    const _Float16* __restrict__ ahi, const _Float16* __restrict__ alo,
    const _Float16* __restrict__ bhi, const _Float16* __restrict__ blo,
    const float* __restrict__ vin, const float* __restrict__ zin,
    float* __restrict__ out) {
  __shared__ __align__(16) _Float16 sbuf[2][4][IMG_HALVES];  // 64 KB

  const int tid = threadIdx.x;
  const int bn = blockIdx.x;
  const int bm = blockIdx.y;
  const int lane = tid & 63;
  const int wid = tid >> 6;
  const int wm = wid & 1;
  const int wn = wid >> 1;
  const int lr = lane & 15;
  const int kg = lane >> 4;

  // staging role: wave wid streams image wid (0=Ahi,1=Alo,2=Bhi,3=Blo)
  const _Float16* gsrc;
  if (wid == 0)      gsrc = ahi + (size_t)bm * 96 * IMG_HALVES;
  else if (wid == 1) gsrc = alo + (size_t)bm * 96 * IMG_HALVES;
  else if (wid == 2) gsrc = bhi + (size_t)bn * 96 * IMG_HALVES;
  else               gsrc = blo + (size_t)bn * 96 * IMG_HALVES;
  gsrc += (size_t)lane * 8;  // per-lane 16 B (matches HW dest lane*16)

  // frag byte offsets within an image (halves): img[kg][row][8]
  const int abase = kg * 1024 + (wm * 64 + lr) * 8;
  const int bbase = kg * 1024 + (wn * 64 + lr) * 8;

  f32x4 acc0[4][4];  // hi*hi (scale 256)
  f32x4 acc1[4][4];  // hi*lo + lo*hi (scale 256*2048)
#pragma unroll
  for (int i = 0; i < 4; ++i)
#pragma unroll
    for (int j = 0; j < 4; ++j) {
      acc0[i][j] = (f32x4)0.0f;
      acc1[i][j] = (f32x4)0.0f;
    }

  // prologue: stage kt=0 into buffer 0
  {
    _Float16* l = &sbuf[0][wid][0];
#pragma unroll
    for (int q = 0; q < 8; ++q)
      __builtin_amdgcn_global_load_lds(GLOBAL_AS(gsrc + q * 512),
                                       LDS_AS(l + q * 512), 16, 0, 0);
  }

  for (int kt = 0; kt < NSTEP; ++kt) {
    __syncthreads();  // drains this wave's DMAs (cur buf ready) + nxt buf free

    if (kt + 1 < NSTEP) {
      const _Float16* g = gsrc + (size_t)(kt + 1) * IMG_HALVES;
      _Float16* l = &sbuf[(kt + 1) & 1][wid][0];
#pragma unroll
      for (int q = 0; q < 8; ++q)
        __builtin_amdgcn_global_load_lds(GLOBAL_AS(g + q * 512),
                                         LDS_AS(l + q * 512), 16, 0, 0);
    }

    const _Float16* pAhi = &sbuf[kt & 1][0][0];
    const _Float16* pAlo = pAhi + IMG_HALVES;
    const _Float16* pBhi = pAhi + 2 * IMG_HALVES;
    const _Float16* pBlo = pAhi + 3 * IMG_HALVES;

    f16x8 ah[4], al[4];
#pragma unroll
    for (int i = 0; i < 4; ++i) {
      ah[i] = *(const f16x8*)&pAhi[abase + i * 16 * 8];
      al[i] = *(const f16x8*)&pAlo[abase + i * 16 * 8];
    }
#pragma unroll
    for (int j = 0; j < 4; ++j) {
      const f16x8 bh = *(const f16x8*)&pBhi[bbase + j * 16 * 8];
      const f16x8 bl = *(const f16x8*)&pBlo[bbase + j * 16 * 8];
#pragma unroll
      for (int i = 0; i < 4; ++i)
        acc0[i][j] = __builtin_amdgcn_mfma_f32_16x16x32_f16(ah[i], bh, acc0[i][j], 0, 0, 0);
#pragma unroll
      for (int i = 0; i < 4; ++i)
        acc1[i][j] = __builtin_amdgcn_mfma_f32_16x16x32_f16(ah[i], bl, acc1[i][j], 0, 0, 0);
#pragma unroll
      for (int i = 0; i < 4; ++i)
        acc1[i][j] = __builtin_amdgcn_mfma_f32_16x16x32_f16(al[i], bh, acc1[i][j], 0, 0, 0);
    }
  }

  // fused LIF epilogue
  const float DECAYF = 0.9512294245007140f;
  const float OMD = 1.0f - DECAYF;
  const float THR = 0.615f;

  float* outZ = out;
  float* outV = out + (size_t)M_DIM * N_DIM;
  const int colbase = bn * 128 + wn * 64;
  const int rowbase = bm * 128 + wm * 64 + kg * 4;

#pragma unroll
  for (int i = 0; i < 4; ++i) {
#pragma unroll
    for (int j = 0; j < 4; ++j) {
      const int col = colbase + j * 16 + lr;
#pragma unroll
      for (int r = 0; r < 4; ++r) {
        const int row = rowbase + i * 16 + r;
        const size_t idx = (size_t)row * N_DIM + col;
        const float it = acc0[i][j][r] * (1.0f / 256.0f) +
                         acc1[i][j][r] * (1.0f / 524288.0f);
        const float vv = vin[idx];
        const float zz = zin[idx];
        const float nv = DECAYF * vv + OMD * it - THR * zz;
        const float vs = (nv - THR) / THR;
        outZ[idx] = (vs > THR) ? 1.0f : 0.0f;
        outV[idx] = nv;
      }
    }
  }
}

// ---------------------------------------------------------------------------
// Fallback (round-1 monolithic kernel) — used only if ws_size < WS_NEEDED.
// ---------------------------------------------------------------------------
#define LDK 40
__global__ __launch_bounds__(256, 2) void lif_kernel(
    const float* __restrict__ inputs, const float* __restrict__ vin,
    const float* __restrict__ zin, const float* __restrict__ w_in,
    const float* __restrict__ w_rec, float* __restrict__ out) {
  __shared__ __align__(16) _Float16 sAhi[128 * LDK];
  __shared__ __align__(16) _Float16 sAlo[128 * LDK];
  __shared__ __align__(16) _Float16 sBhi[128 * LDK];
  __shared__ __align__(16) _Float16 sBlo[128 * LDK];

  const int tid = threadIdx.x;
  const int bn = blockIdx.x;
  const int bm = blockIdx.y;
  const int srow = tid & 127;
  const int skh = tid >> 7;
  const int lane = tid & 63;
  const int wid = tid >> 6;
  const int wm = wid & 1;
  const int wn = wid >> 1;
  const int lr = lane & 15;
  const int kg = lane >> 4;
  const int aoff = (wm * 64 + lr) * LDK + kg * 8;
  const int boff = (wn * 64 + lr) * LDK + kg * 8;

  f32x4 acc0[4][4];
  f32x4 acc1[4][4];
#pragma unroll
  for (int i = 0; i < 4; ++i)
#pragma unroll
    for (int j = 0; j < 4; ++j) {
      acc0[i][j] = (f32x4)0.0f;
      acc1[i][j] = (f32x4)0.0f;
    }

  const int rowg = bm * 128 + srow;
  const int ng = bn * 128 + srow;

  for (int kt = 0; kt < NSTEP; ++kt) {
    const int k0 = kt * BK;
    f16x8 ahi[2], alo[2];
    {
      const float* aptr = (k0 < KA)
          ? inputs + (size_t)rowg * KA + (k0 + skh * 16)
          : zin + (size_t)rowg * N_DIM + (k0 - KA + skh * 16);
#pragma unroll
      for (int q = 0; q < 4; ++q) {
        const float4 f = *(const float4*)(aptr + q * 4);
        const int vi = q >> 1, ei = (q & 1) * 4;
        SPLIT(f.x, ahi[vi], alo[vi], ei + 0);
        SPLIT(f.y, ahi[vi], alo[vi], ei + 1);
        SPLIT(f.z, ahi[vi], alo[vi], ei + 2);
        SPLIT(f.w, ahi[vi], alo[vi], ei + 3);
      }
    }
    f16x8 bhi[2], blo[2];
    {
      const bool isrec = (k0 >= KA);
      const int kbase = k0 - KA + skh * 16;
      const float* bptr = isrec
          ? w_rec + (size_t)kbase * N_DIM + ng
          : w_in + (size_t)(k0 + skh * 16) * N_DIM + ng;
#pragma unroll
      for (int kk = 0; kk < 16; ++kk) {
        float x = bptr[(size_t)kk * N_DIM];
        if (isrec && (kbase + kk == ng)) x = 0.0f;
        x *= 256.0f;
        SPLIT(x, bhi[kk >> 3], blo[kk >> 3], kk & 7);
      }
    }

    __syncthreads();
    {
      _Float16* pA = &sAhi[srow * LDK + skh * 16];
      *(f16x8*)(pA + 0) = ahi[0];
      *(f16x8*)(pA + 8) = ahi[1];
      _Float16* pAl = &sAlo[srow * LDK + skh * 16];
      *(f16x8*)(pAl + 0) = alo[0];
      *(f16x8*)(pAl + 8) = alo[1];
      _Float16* pB = &sBhi[srow * LDK + skh * 16];
      *(f16x8*)(pB + 0) = bhi[0];
      *(f16x8*)(pB + 8) = bhi[1];
      _Float16* pBl = &sBlo[srow * LDK + skh * 16];
      *(f16x8*)(pBl + 0) = blo[0];
      *(f16x8*)(pBl + 8) = blo[1];
    }
    __syncthreads();

    f16x8 ah[4], al[4];
#pragma unroll
    for (int i = 0; i < 4; ++i) {
      ah[i] = *(const f16x8*)&sAhi[aoff + i * 16 * LDK];
      al[i] = *(const f16x8*)&sAlo[aoff + i * 16 * LDK];
    }
#pragma unroll
    for (int j = 0; j < 4; ++j) {
      const f16x8 bh = *(const f16x8*)&sBhi[boff + j * 16 * LDK];
      const f16x8 bl = *(const f16x8*)&sBlo[boff + j * 16 * LDK];
#pragma unroll
      for (int i = 0; i < 4; ++i)
        acc0[i][j] = __builtin_amdgcn_mfma_f32_16x16x32_f16(ah[i], bh, acc0[i][j], 0, 0, 0);
#pragma unroll
      for (int i = 0; i < 4; ++i)
        acc1[i][j] = __builtin_amdgcn_mfma_f32_16x16x32_f16(ah[i], bl, acc1[i][j], 0, 0, 0);
#pragma unroll
      for (int i = 0; i < 4; ++i)
        acc1[i][j] = __builtin_amdgcn_mfma_f32_16x16x32_f16(al[i], bh, acc1[i][j], 0, 0, 0);
    }
  }

  const float DECAYF = 0.9512294245007140f;
  const float OMD = 1.0f - DECAYF;
  const float THR = 0.615f;
  float* outZ = out;
  float* outV = out + (size_t)M_DIM * N_DIM;
  const int colbase = bn * 128 + wn * 64;
  const int rowbase = bm * 128 + wm * 64 + kg * 4;
#pragma unroll
  for (int i = 0; i < 4; ++i) {
#pragma unroll
    for (int j = 0; j < 4; ++j) {
      const int col = colbase + j * 16 + lr;
#pragma unroll
      for (int r = 0; r < 4; ++r) {
        const int row = rowbase + i * 16 + r;
        const size_t idx = (size_t)row * N_DIM + col;
        const float it = acc0[i][j][r] * (1.0f / 256.0f) +
                         acc1[i][j][r] * (1.0f / 524288.0f);
        const float vv = vin[idx];
        const float zz = zin[idx];
        const float nv = DECAYF * vv + OMD * it - THR * zz;
        const float vs = (nv - THR) / THR;
        outZ[idx] = (vs > THR) ? 1.0f : 0.0f;
        outV[idx] = nv;
      }
    }
  }
}

extern "C" void kernel_launch(void* const* d_in, const int* in_sizes, int n_in,
                              void* d_out, int out_size, void* d_ws, size_t ws_size,
                              hipStream_t stream) {
  const float* inputs = (const float*)d_in[0];
  const float* v      = (const float*)d_in[1];
  const float* z      = (const float*)d_in[2];
  const float* w_in   = (const float*)d_in[3];
  const float* w_rec  = (const float*)d_in[4];
  float* out = (float*)d_out;

  if (ws_size >= WS_NEEDED) {
    _Float16* ahi = (_Float16*)d_ws;
    _Float16* alo = (_Float16*)((char*)d_ws + SZ_A);
    _Float16* bhi = (_Float16*)((char*)d_ws + 2 * SZ_A);
    _Float16* blo = (_Float16*)((char*)d_ws + 2 * SZ_A + SZ_B);
    hipLaunchKernelGGL(prep_a, dim3(96, 32), dim3(256), 0, stream,
                       inputs, z, ahi, alo);
    hipLaunchKernelGGL(prep_b, dim3(96, 16), dim3(128), 0, stream,
                       w_in, w_rec, bhi, blo);
    hipLaunchKernelGGL(lif_gemm, dim3(16, 32), dim3(256), 0, stream,
                       ahi, alo, bhi, blo, v, z, out);
  } else {
    hipLaunchKernelGGL(lif_kernel, dim3(16, 32), dim3(256), 0, stream,
                       inputs, v, z, w_in, w_rec, out);
  }
}

// Round 4
// 300.055 us; speedup vs baseline: 1.3260x; 1.0358x over previous
//
#include <hip/hip_runtime.h>

// LightLIF fused step on MI355X (gfx950) — round 4.
//
//   A = [inputs | z]            : [4096, 3072] fp32   (M x K)
//   Bm = [w_in ; w_rec*(1-eye)] : [3072, 2048] fp32   (K x N), B pre-scaled by 256
//   i_t = A @ Bm    (fp32-accurate via f16 Markidis split, 3 MFMA passes)
//   new_v = DECAY*v + (1-DECAY)*i_t - 0.615*z ; spike vs THR
//   d_out = [new_z (M*N) | new_v (M*N)]
//
// Round-4: 256x128 C-tile per block (512 thr, 8 waves of 64x64) to cut image
// traffic 1.54 -> 1.15 GB (feed-bound regime per round-3 counters). Images in
// k-octet-major layout (A: [kg4][row256][8], B: [kg4][col128][8]) staged by
// global_load_lds width=16; double-buffered 96 KB dynamic LDS; one barrier
// per K-step. Grid 16x16 = 256 blocks = exactly 1/CU; default XCD round-robin
// gives each XCD 2 bn-streams -> B mostly L2-resident. Numerics bit-identical
// to rounds 1-3.

#define M_DIM 4096
#define N_DIM 2048
#define K_DIM 3072
#define KA    1024
#define BK    32
#define NSTEP (K_DIM / BK)          // 96
#define AIMG  8192                  // halves: 4 k-octets x 256 rows x 8
#define BIMG  4096                  // halves: 4 k-octets x 128 cols x 8
#define BUF_HALVES (2 * AIMG + 2 * BIMG)  // 24576 halves = 48 KB per buffer

#define SZ_AH ((size_t)16 * 96 * AIMG * 2)  // 25,165,824 B (one of hi/lo)
#define SZ_BH ((size_t)16 * 96 * BIMG * 2)  // 12,582,912 B
#define WS_NEEDED (2 * SZ_AH + 2 * SZ_BH)   // 75,497,472 B

typedef _Float16 f16x8 __attribute__((ext_vector_type(8)));
typedef float    f32x4 __attribute__((ext_vector_type(4)));

#define GLOBAL_AS(p) ((const __attribute__((address_space(1))) void*)(p))
#define LDS_AS(p)    ((__attribute__((address_space(3))) void*)(p))

// hi/lo split with lo pre-scaled by 2048 (RNE conversions)
#define SPLIT(x, dsthi, dstlo, idx)                                  \
  {                                                                  \
    _Float16 _h = (_Float16)(x);                                     \
    float    _r = ((x) - (float)_h) * 2048.0f;                       \
    dsthi[idx] = _h;                                                 \
    dstlo[idx] = (_Float16)_r;                                       \
  }

// ---------------------------------------------------------------------------
// prep_a: split [inputs|z] into (hi,lo) f16 images, layout [kg][row 256][8].
// grid (96 kt, 16 bm), block 256. Lane owns one k-octet of one row (32 B read,
// 2 lanes cover a 64 B granule); stores f16x8 dense.
// ---------------------------------------------------------------------------
__global__ void prep_a(const float* __restrict__ inputs,
                       const float* __restrict__ z,
                       _Float16* __restrict__ ahi, _Float16* __restrict__ alo) {
  const int kt = blockIdx.x, bm = blockIdx.y;
  const int t = threadIdx.x;
  const int s = t & 3;       // k-octet 0..3
  const int rr = t >> 2;     // 0..63
  const int k0 = kt * BK + s * 8;
  const size_t img = ((size_t)bm * 96 + kt) * AIMG;
#pragma unroll
  for (int p = 0; p < 4; ++p) {
    const int row = p * 64 + rr;
    const int rg = bm * 256 + row;
    const float* src = (kt < 32) ? inputs + (size_t)rg * KA + k0
                                 : z + (size_t)rg * N_DIM + (k0 - KA);
    const float4 f0 = *(const float4*)(src);
    const float4 f1 = *(const float4*)(src + 4);
    f16x8 hi, lo;
    SPLIT(f0.x, hi, lo, 0);
    SPLIT(f0.y, hi, lo, 1);
    SPLIT(f0.z, hi, lo, 2);
    SPLIT(f0.w, hi, lo, 3);
    SPLIT(f1.x, hi, lo, 4);
    SPLIT(f1.y, hi, lo, 5);
    SPLIT(f1.z, hi, lo, 6);
    SPLIT(f1.w, hi, lo, 7);
    const size_t o = img + (size_t)s * 2048 + (size_t)row * 8;
    *(f16x8*)&ahi[o] = hi;
    *(f16x8*)&alo[o] = lo;
  }
}

// ---------------------------------------------------------------------------
// prep_b: split w (x256, diag-masked) into transposed images [kg][col 128][8].
// grid (96 kt, 16 bn), block 128; thread owns one output column.
// ---------------------------------------------------------------------------
__global__ void prep_b(const float* __restrict__ w_in,
                       const float* __restrict__ w_rec,
                       _Float16* __restrict__ bhi, _Float16* __restrict__ blo) {
  const int kt = blockIdx.x, bn = blockIdx.y;
  const int c = threadIdx.x;      // 0..127
  const int ng = bn * 128 + c;
  const int k0 = kt * BK;
  f16x8 hi[4], lo[4];
#pragma unroll
  for (int kk = 0; kk < BK; ++kk) {
    const int k = k0 + kk;
    float x = (k < KA) ? w_in[(size_t)k * N_DIM + ng]
                       : w_rec[(size_t)(k - KA) * N_DIM + ng];
    if (k >= KA && (k - KA) == ng) x = 0.0f;   // zero diagonal of w_rec
    x *= 256.0f;                               // keep hi-parts normal in f16
    SPLIT(x, hi[kk >> 3], lo[kk >> 3], kk & 7);
  }
  const size_t img = ((size_t)bn * 96 + kt) * BIMG + (size_t)c * 8;
#pragma unroll
  for (int q = 0; q < 4; ++q) {
    *(f16x8*)&bhi[img + (size_t)q * 1024] = hi[q];
    *(f16x8*)&blo[img + (size_t)q * 1024] = lo[q];
  }
}

// ---------------------------------------------------------------------------
// GEMM + fused LIF epilogue. grid (16 bn, 16 bm), block 512 (8 waves, 4m x 2n
// of 64x64). Double-buffered 96 KB dynamic LDS; waves 0-3 stage A (8 KB each),
// waves 4-7 stage B (4 KB each); ONE barrier per K-step.
// ---------------------------------------------------------------------------
__global__ __launch_bounds__(512, 2) void lif_gemm(
    const _Float16* __restrict__ ahi, const _Float16* __restrict__ alo,
    const _Float16* __restrict__ bhi, const _Float16* __restrict__ blo,
    const float* __restrict__ vin, const float* __restrict__ zin,
    float* __restrict__ out) {
  extern __shared__ __align__(16) _Float16 sbuf[];  // 2 * BUF_HALVES = 96 KB

  const int tid = threadIdx.x;
  const int bn = blockIdx.x;
  const int bm = blockIdx.y;
  const int lane = tid & 63;
  const int wid = tid >> 6;       // 0..7
  const int wm = wid & 3;         // m-quadrant (4 x 64)
  const int wn = wid >> 2;        // n-half (2 x 64)
  const int lr = lane & 15;
  const int kg = lane >> 4;

  // staging role: waves 0-1 -> Ahi, 2-3 -> Alo, 4-5 -> Bhi, 6-7 -> Blo
  const _Float16* gsrc;
  int lofs;        // wave's slice offset within a buffer (halves)
  size_t gstep;    // per-K-step stride in halves
  const bool awave = (wid < 4);
  if (wid < 2) {
    gsrc = ahi + ((size_t)bm * 96) * AIMG + wid * 4096;
    lofs = wid * 4096;            gstep = AIMG;
  } else if (wid < 4) {
    gsrc = alo + ((size_t)bm * 96) * AIMG + (wid - 2) * 4096;
    lofs = AIMG + (wid - 2) * 4096; gstep = AIMG;
  } else if (wid < 6) {
    gsrc = bhi + ((size_t)bn * 96) * BIMG + (wid - 4) * 2048;
    lofs = 2 * AIMG + (wid - 4) * 2048; gstep = BIMG;
  } else {
    gsrc = blo + ((size_t)bn * 96) * BIMG + (wid - 6) * 2048;
    lofs = 2 * AIMG + BIMG + (wid - 6) * 2048; gstep = BIMG;
  }
  gsrc += (size_t)lane * 8;  // per-lane 16 B (matches HW dest lane*16)

  // frag offsets (halves): A image [kg][row][8], B image [kg][col][8]
  const int abase = kg * 2048 + (wm * 64 + lr) * 8;
  const int bbase = kg * 1024 + (wn * 64 + lr) * 8;

  f32x4 acc0[4][4];  // hi*hi (scale 256)
  f32x4 acc1[4][4];  // hi*lo + lo*hi (scale 256*2048)
#pragma unroll
  for (int i = 0; i < 4; ++i)
#pragma unroll
    for (int j = 0; j < 4; ++j) {
      acc0[i][j] = (f32x4)0.0f;
      acc1[i][j] = (f32x4)0.0f;
    }

  // prologue: stage kt=0 into buffer 0
  {
    _Float16* l = sbuf + lofs;
#pragma unroll
    for (int q = 0; q < 4; ++q)
      __builtin_amdgcn_global_load_lds(GLOBAL_AS(gsrc + q * 512),
                                       LDS_AS(l + q * 512), 16, 0, 0);
    if (awave) {
#pragma unroll
      for (int q = 4; q < 8; ++q)
        __builtin_amdgcn_global_load_lds(GLOBAL_AS(gsrc + q * 512),
                                         LDS_AS(l + q * 512), 16, 0, 0);
    }
  }

  for (int kt = 0; kt < NSTEP; ++kt) {
    __syncthreads();  // cur buf staged; nxt buf's consumers done

    if (kt + 1 < NSTEP) {
      const _Float16* g = gsrc + (size_t)(kt + 1) * gstep;
      _Float16* l = sbuf + ((kt + 1) & 1) * BUF_HALVES + lofs;
#pragma unroll
      for (int q = 0; q < 4; ++q)
        __builtin_amdgcn_global_load_lds(GLOBAL_AS(g + q * 512),
                                         LDS_AS(l + q * 512), 16, 0, 0);
      if (awave) {
#pragma unroll
        for (int q = 4; q < 8; ++q)
          __builtin_amdgcn_global_load_lds(GLOBAL_AS(g + q * 512),
                                           LDS_AS(l + q * 512), 16, 0, 0);
      }
    }

    const _Float16* base = sbuf + (kt & 1) * BUF_HALVES;
    const _Float16* pAhi = base;
    const _Float16* pAlo = base + AIMG;
    const _Float16* pBhi = base + 2 * AIMG;
    const _Float16* pBlo = base + 2 * AIMG + BIMG;

    f16x8 ah[4], al[4];
#pragma unroll
    for (int i = 0; i < 4; ++i) {
      ah[i] = *(const f16x8*)&pAhi[abase + i * 128];
      al[i] = *(const f16x8*)&pAlo[abase + i * 128];
    }
#pragma unroll
    for (int j = 0; j < 4; ++j) {
      const f16x8 bh = *(const f16x8*)&pBhi[bbase + j * 128];
      const f16x8 bl = *(const f16x8*)&pBlo[bbase + j * 128];
#pragma unroll
      for (int i = 0; i < 4; ++i)
        acc0[i][j] = __builtin_amdgcn_mfma_f32_16x16x32_f16(ah[i], bh, acc0[i][j], 0, 0, 0);
#pragma unroll
      for (int i = 0; i < 4; ++i)
        acc1[i][j] = __builtin_amdgcn_mfma_f32_16x16x32_f16(ah[i], bl, acc1[i][j], 0, 0, 0);
#pragma unroll
      for (int i = 0; i < 4; ++i)
        acc1[i][j] = __builtin_amdgcn_mfma_f32_16x16x32_f16(al[i], bh, acc1[i][j], 0, 0, 0);
    }
  }

  // fused LIF epilogue
  const float DECAYF = 0.9512294245007140f;
  const float OMD = 1.0f - DECAYF;
  const float THR = 0.615f;

  float* outZ = out;
  float* outV = out + (size_t)M_DIM * N_DIM;
  const int colbase = bn * 128 + wn * 64;
  const int rowbase = bm * 256 + wm * 64 + kg * 4;

#pragma unroll
  for (int i = 0; i < 4; ++i) {
#pragma unroll
    for (int j = 0; j < 4; ++j) {
      const int col = colbase + j * 16 + lr;
#pragma unroll
      for (int r = 0; r < 4; ++r) {
        const int row = rowbase + i * 16 + r;
        const size_t idx = (size_t)row * N_DIM + col;
        const float it = acc0[i][j][r] * (1.0f / 256.0f) +
                         acc1[i][j][r] * (1.0f / 524288.0f);
        const float vv = vin[idx];
        const float zz = zin[idx];
        const float nv = DECAYF * vv + OMD * it - THR * zz;
        const float vs = (nv - THR) / THR;
        outZ[idx] = (vs > THR) ? 1.0f : 0.0f;
        outV[idx] = nv;
      }
    }
  }
}

// ---------------------------------------------------------------------------
// Fallback (round-1 monolithic kernel) — used only if ws_size < WS_NEEDED.
// ---------------------------------------------------------------------------
#define LDK 40
__global__ __launch_bounds__(256, 2) void lif_kernel(
    const float* __restrict__ inputs, const float* __restrict__ vin,
    const float* __restrict__ zin, const float* __restrict__ w_in,
    const float* __restrict__ w_rec, float* __restrict__ out) {
  __shared__ __align__(16) _Float16 sAhi[128 * LDK];
  __shared__ __align__(16) _Float16 sAlo[128 * LDK];
  __shared__ __align__(16) _Float16 sBhi[128 * LDK];
  __shared__ __align__(16) _Float16 sBlo[128 * LDK];

  const int tid = threadIdx.x;
  const int bn = blockIdx.x;
  const int bm = blockIdx.y;
  const int srow = tid & 127;
  const int skh = tid >> 7;
  const int lane = tid & 63;
  const int wid = tid >> 6;
  const int wm = wid & 1;
  const int wn = wid >> 1;
  const int lr = lane & 15;
  const int kg = lane >> 4;
  const int aoff = (wm * 64 + lr) * LDK + kg * 8;
  const int boff = (wn * 64 + lr) * LDK + kg * 8;

  f32x4 acc0[4][4];
  f32x4 acc1[4][4];
#pragma unroll
  for (int i = 0; i < 4; ++i)
#pragma unroll
    for (int j = 0; j < 4; ++j) {
      acc0[i][j] = (f32x4)0.0f;
      acc1[i][j] = (f32x4)0.0f;
    }

  const int rowg = bm * 128 + srow;
  const int ng = bn * 128 + srow;

  for (int kt = 0; kt < NSTEP; ++kt) {
    const int k0 = kt * BK;
    f16x8 ahi[2], alo[2];
    {
      const float* aptr = (k0 < KA)
          ? inputs + (size_t)rowg * KA + (k0 + skh * 16)
          : zin + (size_t)rowg * N_DIM + (k0 - KA + skh * 16);
#pragma unroll
      for (int q = 0; q < 4; ++q) {
        const float4 f = *(const float4*)(aptr + q * 4);
        const int vi = q >> 1, ei = (q & 1) * 4;
        SPLIT(f.x, ahi[vi], alo[vi], ei + 0);
        SPLIT(f.y, ahi[vi], alo[vi], ei + 1);
        SPLIT(f.z, ahi[vi], alo[vi], ei + 2);
        SPLIT(f.w, ahi[vi], alo[vi], ei + 3);
      }
    }
    f16x8 bhi[2], blo[2];
    {
      const bool isrec = (k0 >= KA);
      const int kbase = k0 - KA + skh * 16;
      const float* bptr = isrec
          ? w_rec + (size_t)kbase * N_DIM + ng
          : w_in + (size_t)(k0 + skh * 16) * N_DIM + ng;
#pragma unroll
      for (int kk = 0; kk < 16; ++kk) {
        float x = bptr[(size_t)kk * N_DIM];
        if (isrec && (kbase + kk == ng)) x = 0.0f;
        x *= 256.0f;
        SPLIT(x, bhi[kk >> 3], blo[kk >> 3], kk & 7);
      }
    }

    __syncthreads();
    {
      _Float16* pA = &sAhi[srow * LDK + skh * 16];
      *(f16x8*)(pA + 0) = ahi[0];
      *(f16x8*)(pA + 8) = ahi[1];
      _Float16* pAl = &sAlo[srow * LDK + skh * 16];
      *(f16x8*)(pAl + 0) = alo[0];
      *(f16x8*)(pAl + 8) = alo[1];
      _Float16* pB = &sBhi[srow * LDK + skh * 16];
      *(f16x8*)(pB + 0) = bhi[0];
      *(f16x8*)(pB + 8) = bhi[1];
      _Float16* pBl = &sBlo[srow * LDK + skh * 16];
      *(f16x8*)(pBl + 0) = blo[0];
      *(f16x8*)(pBl + 8) = blo[1];
    }
    __syncthreads();

    f16x8 ah[4], al[4];
#pragma unroll
    for (int i = 0; i < 4; ++i) {
      ah[i] = *(const f16x8*)&sAhi[aoff + i * 16 * LDK];
      al[i] = *(const f16x8*)&sAlo[aoff + i * 16 * LDK];
    }
#pragma unroll
    for (int j = 0; j < 4; ++j) {
      const f16x8 bh = *(const f16x8*)&sBhi[boff + j * 16 * LDK];
      const f16x8 bl = *(const f16x8*)&sBlo[boff + j * 16 * LDK];
#pragma unroll
      for (int i = 0; i < 4; ++i)
        acc0[i][j] = __builtin_amdgcn_mfma_f32_16x16x32_f16(ah[i], bh, acc0[i][j], 0, 0, 0);
#pragma unroll
      for (int i = 0; i < 4; ++i)
        acc1[i][j] = __builtin_amdgcn_mfma_f32_16x16x32_f16(ah[i], bl, acc1[i][j], 0, 0, 0);
#pragma unroll
      for (int i = 0; i < 4; ++i)
        acc1[i][j] = __builtin_amdgcn_mfma_f32_16x16x32_f16(al[i], bh, acc1[i][j], 0, 0, 0);
    }
  }

  const float DECAYF = 0.9512294245007140f;
  const float OMD = 1.0f - DECAYF;
  const float THR = 0.615f;
  float* outZ = out;
  float* outV = out + (size_t)M_DIM * N_DIM;
  const int colbase = bn * 128 + wn * 64;
  const int rowbase = bm * 128 + wm * 64 + kg * 4;
#pragma unroll
  for (int i = 0; i < 4; ++i) {
#pragma unroll
    for (int j = 0; j < 4; ++j) {
      const int col = colbase + j * 16 + lr;
#pragma unroll
      for (int r = 0; r < 4; ++r) {
        const int row = rowbase + i * 16 + r;
        const size_t idx = (size_t)row * N_DIM + col;
        const float it = acc0[i][j][r] * (1.0f / 256.0f) +
                         acc1[i][j][r] * (1.0f / 524288.0f);
        const float vv = vin[idx];
        const float zz = zin[idx];
        const float nv = DECAYF * vv + OMD * it - THR * zz;
        const float vs = (nv - THR) / THR;
        outZ[idx] = (vs > THR) ? 1.0f : 0.0f;
        outV[idx] = nv;
      }
    }
  }
}

extern "C" void kernel_launch(void* const* d_in, const int* in_sizes, int n_in,
                              void* d_out, int out_size, void* d_ws, size_t ws_size,
                              hipStream_t stream) {
  const float* inputs = (const float*)d_in[0];
  const float* v      = (const float*)d_in[1];
  const float* z      = (const float*)d_in[2];
  const float* w_in   = (const float*)d_in[3];
  const float* w_rec  = (const float*)d_in[4];
  float* out = (float*)d_out;

  if (ws_size >= WS_NEEDED) {
    _Float16* ahi = (_Float16*)d_ws;
    _Float16* alo = (_Float16*)((char*)d_ws + SZ_AH);
    _Float16* bhi = (_Float16*)((char*)d_ws + 2 * SZ_AH);
    _Float16* blo = (_Float16*)((char*)d_ws + 2 * SZ_AH + SZ_BH);

    // allow 96 KB dynamic LDS (gfx950 has 160 KB/CU); idempotent, capture-safe
    static_assert(2 * BUF_HALVES * sizeof(_Float16) == 98304, "LDS size");
    (void)hipFuncSetAttribute((const void*)lif_gemm,
                              hipFuncAttributeMaxDynamicSharedMemorySize, 98304);

    hipLaunchKernelGGL(prep_a, dim3(96, 16), dim3(256), 0, stream,
                       inputs, z, ahi, alo);
    hipLaunchKernelGGL(prep_b, dim3(96, 16), dim3(128), 0, stream,
                       w_in, w_rec, bhi, blo);
    hipLaunchKernelGGL(lif_gemm, dim3(16, 16), dim3(512), 98304, stream,
                       ahi, alo, bhi, blo, v, z, out);
  } else {
    hipLaunchKernelGGL(lif_kernel, dim3(16, 32), dim3(256), 0, stream,
                       inputs, v, z, w_in, w_rec, out);
  }
}